// Round 4
// baseline (2570.210 us; speedup 1.0000x reference)
//
#include <hip/hip_runtime.h>
#include <hip/hip_bf16.h>

#define BB 128
#define TT 200
#define TM1 199
#define EQ 128
#define CC 64
#define VV 128
#define SS 256
#define NQ1 5001

typedef __attribute__((ext_vector_type(8))) short short8;
typedef __attribute__((ext_vector_type(4))) float f32x4;

__device__ __forceinline__ float sigmoidf_(float x) { return 1.f / (1.f + __expf(-x)); }
__device__ __forceinline__ float ftanh(float x) {
    x = fminf(fmaxf(x, -15.f), 15.f);
    float e = __expf(2.f * x);
    return (e - 1.f) / (e + 1.f);
}
// fp32 -> bf16 bits, round-to-nearest-even (finite inputs only)
__device__ __forceinline__ unsigned short f2bf(float f) {
    unsigned int u = __float_as_uint(f);
    unsigned int r = u + 0x7FFFu + ((u >> 16) & 1u);
    return (unsigned short)(r >> 16);
}

// ---------------------------------------------------------------------------
// Kernel 0: convert Wob (5001x256 fp32) -> bf16 for MFMA use.
// ---------------------------------------------------------------------------
__global__ __launch_bounds__(256) void k_cvt(
    const float* __restrict__ src, unsigned short* __restrict__ dst, int n4)
{
    int i4 = blockIdx.x * 256 + threadIdx.x;
    if (i4 < n4) {
        float4 v = ((const float4*)src)[i4];
        ushort4 o;
        o.x = f2bf(v.x); o.y = f2bf(v.y); o.z = f2bf(v.z); o.w = f2bf(v.w);
        ((ushort4*)dst)[i4] = o;
    }
}

// ---------------------------------------------------------------------------
// Kernel 1: per-(b,t) front: corr = softmax((qe@Wk.T+bk) @ KM.T), erase, add.
// 4 rows per block, 128 threads. All inputs fp32.
// ---------------------------------------------------------------------------
__global__ __launch_bounds__(128) void k_front(
    const int* __restrict__ qd, const int* __restrict__ ad,
    const float* __restrict__ q_embed, const float* __restrict__ a_embed,
    const float* __restrict__ key_matrix,
    const float* __restrict__ Wk, const float* __restrict__ bk,
    const float* __restrict__ We, const float* __restrict__ be,
    const float* __restrict__ We2, const float* __restrict__ be2,
    const float* __restrict__ Wa, const float* __restrict__ ba,
    const float* __restrict__ Wa2, const float* __restrict__ ba2,
    float* __restrict__ corr, float* __restrict__ erase, float* __restrict__ addb)
{
    __shared__ float qa[4][256];
    __shared__ float rk[4][128];
    __shared__ float he[4][128];
    __shared__ float ha[4][128];

    const int tid = threadIdx.x;          // 0..127
    const int m0 = blockIdx.x * 4;        // row = b*T + t

    for (int r = 0; r < 4; r++) {
        int m = m0 + r;
        int qi = qd[m];
        int ai = ad[m];
        qa[r][tid]       = q_embed[(size_t)qi * EQ + tid];
        qa[r][128 + tid] = a_embed[(size_t)ai * EQ + tid];
    }
    __syncthreads();

    const int j = tid;
    float accK[4] = {0, 0, 0, 0};
    float accE[4] = {0, 0, 0, 0};
    float accA[4] = {0, 0, 0, 0};
    for (int k4 = 0; k4 < 128; k4 += 4) {
        float4 w = *(const float4*)(Wk + (size_t)j * 128 + k4);
        float wf[4] = {w.x, w.y, w.z, w.w};
#pragma unroll
        for (int i = 0; i < 4; i++)
#pragma unroll
            for (int r = 0; r < 4; r++)
                accK[r] = fmaf(wf[i], qa[r][k4 + i], accK[r]);
    }
    for (int k4 = 0; k4 < 256; k4 += 4) {
        float4 we = *(const float4*)(We + (size_t)j * 256 + k4);
        float4 wa = *(const float4*)(Wa + (size_t)j * 256 + k4);
        float ef[4] = {we.x, we.y, we.z, we.w};
        float af[4] = {wa.x, wa.y, wa.z, wa.w};
#pragma unroll
        for (int i = 0; i < 4; i++)
#pragma unroll
            for (int r = 0; r < 4; r++) {
                accE[r] = fmaf(ef[i], qa[r][k4 + i], accE[r]);
                accA[r] = fmaf(af[i], qa[r][k4 + i], accA[r]);
            }
    }
    float bkj = bk[j], bej = be[j], baj = ba[j];
#pragma unroll
    for (int r = 0; r < 4; r++) {
        rk[r][j] = accK[r] + bkj;
        he[r][j] = accE[r] + bej;
        ha[r][j] = accA[r] + baj;
    }
    __syncthreads();

    const int v = tid;
    float aE[4] = {0, 0, 0, 0};
    float aA[4] = {0, 0, 0, 0};
    for (int j4 = 0; j4 < 128; j4 += 4) {
        float4 w2  = *(const float4*)(We2 + (size_t)v * 128 + j4);
        float4 wa2 = *(const float4*)(Wa2 + (size_t)v * 128 + j4);
        float ef[4] = {w2.x, w2.y, w2.z, w2.w};
        float af[4] = {wa2.x, wa2.y, wa2.z, wa2.w};
#pragma unroll
        for (int i = 0; i < 4; i++)
#pragma unroll
            for (int r = 0; r < 4; r++) {
                aE[r] = fmaf(ef[i], he[r][j4 + i], aE[r]);
                aA[r] = fmaf(af[i], ha[r][j4 + i], aA[r]);
            }
    }
    float be2v = be2[v], ba2v = ba2[v];
#pragma unroll
    for (int r = 0; r < 4; r++) {
        size_t m = (size_t)(m0 + r);
        erase[m * VV + v] = sigmoidf_(aE[r] + be2v);
        addb[m * VV + v]  = ftanh(aA[r] + ba2v);
    }

    // logits + softmax over C=64 (wave 0 only; wave-uniform branch)
    if (tid < 64) {
        const int c = tid;
        float lg[4] = {0, 0, 0, 0};
        for (int k4 = 0; k4 < 128; k4 += 4) {
            float4 km = *(const float4*)(key_matrix + (size_t)c * 128 + k4);
            float kf[4] = {km.x, km.y, km.z, km.w};
#pragma unroll
            for (int i = 0; i < 4; i++)
#pragma unroll
                for (int r = 0; r < 4; r++)
                    lg[r] = fmaf(kf[i], rk[r][k4 + i], lg[r]);
        }
#pragma unroll
        for (int r = 0; r < 4; r++) {
            float x = lg[r];
            float mx = x;
            for (int o = 32; o > 0; o >>= 1) mx = fmaxf(mx, __shfl_xor(mx, o, 64));
            float ex = __expf(x - mx);
            float sm = ex;
            for (int o = 32; o > 0; o >>= 1) sm += __shfl_xor(sm, o, 64);
            corr[(size_t)(m0 + r) * CC + c] = ex / sm;
        }
    }
}

// ---------------------------------------------------------------------------
// Kernel 2: sequential scan over t. One block per batch b; 256 threads:
// v = tid&127, h = tid>>7 covers c in [h*32, h*32+32). M kept in registers.
// ---------------------------------------------------------------------------
__global__ __launch_bounds__(256) void k_scan(
    const float* __restrict__ value_init,
    const float* __restrict__ corr, const float* __restrict__ erase,
    const float* __restrict__ addb,
    float* __restrict__ rc, float* __restrict__ rcn)
{
    const int b = blockIdx.x;
    const int tid = threadIdx.x;
    const int v = tid & 127;
    const int h = tid >> 7;

    float M[32];
#pragma unroll
    for (int i = 0; i < 32; i++)
        M[i] = value_init[(size_t)(h * 32 + i) * VV + v];

    __shared__ float w[64], wn[64], p1[128], q1[128];

    const float* corr_b = corr + (size_t)b * TT * CC;
    const float* er_b   = erase + (size_t)b * TT * VV;
    const float* ad_b   = addb + (size_t)b * TT * VV;
    float* rc_b  = rc  + (size_t)b * TM1 * VV;
    float* rcn_b = rcn + (size_t)b * TM1 * VV;

    for (int t = 0; t < TM1; t++) {
        if (tid < 64) w[tid] = corr_b[t * CC + tid];
        else if (tid < 128) wn[tid - 64] = corr_b[(t + 1) * CC + (tid - 64)];
        float e = er_b[t * VV + v];
        float a = ad_b[t * VV + v];
        __syncthreads();

        float prc = 0.f, prn = 0.f;
#pragma unroll
        for (int i = 0; i < 32; i++) {
            float wc  = w[h * 32 + i];
            float wnc = wn[h * 32 + i];
            float m = M[i];
            m = fmaf(wc, a, m * (1.f - wc * e));
            M[i] = m;
            prc = fmaf(wc, m, prc);
            prn = fmaf(wnc, m, prn);
        }
        if (h == 1) { p1[v] = prc; q1[v] = prn; }
        __syncthreads();
        if (h == 0) {
            rc_b[t * VV + v]  = prc + p1[v];
            rcn_b[t * VV + v] = prn + q1[v];
        }
        __syncthreads();
    }
}

// ---------------------------------------------------------------------------
// Kernel 3: head — pred = sigmoid(tanh(mastery@Ws.T+bs)@Wo.T+bo) [fp32 out],
// tanh_b = tanh(behavior@Wsb.T+bsb) stored bf16. 4 rows/block, 256 threads.
// ---------------------------------------------------------------------------
__global__ __launch_bounds__(256) void k_pred(
    const int* __restrict__ qd, const float* __restrict__ q_embed,
    const float* __restrict__ rc, const float* __restrict__ rcn,
    const float* __restrict__ Ws, const float* __restrict__ bs,
    const float* __restrict__ Wo, const float* __restrict__ bo,
    const float* __restrict__ Wsb, const float* __restrict__ bsb,
    unsigned short* __restrict__ tanhb, float* __restrict__ pred)
{
    __shared__ float mast[4][256];
    __shared__ float beh[4][256];
    __shared__ float red[4][4];

    const int tid = threadIdx.x;   // 0..255
    const int m0 = blockIdx.x * 4; // row = b*199 + t

    for (int r = 0; r < 4; r++) {
        int m = m0 + r;
        int b = m / TM1, t = m % TM1;
        if (tid < 128) {
            mast[r][tid] = rcn[(size_t)m * VV + tid];
            beh[r][tid]  = rc[(size_t)m * VV + tid];
        } else {
            int jj = tid - 128;
            mast[r][tid] = q_embed[(size_t)qd[b * TT + t + 1] * EQ + jj];
            beh[r][tid]  = q_embed[(size_t)qd[b * TT + t] * EQ + jj];
        }
    }
    __syncthreads();

    const int j = tid;
    float hs[4] = {0, 0, 0, 0};
    float hb[4] = {0, 0, 0, 0};
    for (int k4 = 0; k4 < 256; k4 += 4) {
        float4 ws  = *(const float4*)(Ws  + (size_t)j * 256 + k4);
        float4 wsb = *(const float4*)(Wsb + (size_t)j * 256 + k4);
        float sf[4] = {ws.x, ws.y, ws.z, ws.w};
        float bf[4] = {wsb.x, wsb.y, wsb.z, wsb.w};
#pragma unroll
        for (int i = 0; i < 4; i++)
#pragma unroll
            for (int r = 0; r < 4; r++) {
                hs[r] = fmaf(sf[i], mast[r][k4 + i], hs[r]);
                hb[r] = fmaf(bf[i], beh[r][k4 + i], hb[r]);
            }
    }
    float bsj = bs[j], bsbj = bsb[j], woj = Wo[j];
    float pr[4];
#pragma unroll
    for (int r = 0; r < 4; r++) {
        float th = ftanh(hs[r] + bsj);
        float tb = ftanh(hb[r] + bsbj);
        tanhb[(size_t)(m0 + r) * SS + j] = f2bf(tb);
        pr[r] = th * woj;
    }
    const int lane = tid & 63, wv = tid >> 6;
#pragma unroll
    for (int r = 0; r < 4; r++)
        for (int o = 32; o > 0; o >>= 1) pr[r] += __shfl_xor(pr[r], o, 64);
    if (lane == 0)
#pragma unroll
        for (int r = 0; r < 4; r++) red[wv][r] = pr[r];
    __syncthreads();
    if (tid == 0) {
        float bof = bo[0];
#pragma unroll
        for (int r = 0; r < 4; r++) {
            float s = red[0][r] + red[1][r] + red[2][r] + red[3][r] + bof;
            pred[m0 + r] = sigmoidf_(s);
        }
    }
}

// ---------------------------------------------------------------------------
// Kernel 4: big GEMM — out[m,n] = sigmoid(tanhb[m,:] . Wob_bf[n,:] + bob[n]).
// MFMA 16x16x32 bf16, one wave per 16x16 tile, 4 waves/block. fp32 output.
// grid = (ceil(313/4)=79, 25472/16=1592), block = 256.
// ---------------------------------------------------------------------------
__global__ __launch_bounds__(256) void k_big(
    const unsigned short* __restrict__ tanhb,   // M x 256 bf16
    const unsigned short* __restrict__ wob_bf,  // 5001 x 256 bf16
    const float* __restrict__ bob,              // 5001 fp32
    float* __restrict__ out)                    // M x 5001 fp32
{
    const int wid = threadIdx.x >> 6;
    const int lane = threadIdx.x & 63;
    const int mt = blockIdx.y;
    const int nt = blockIdx.x * 4 + wid;
    if (nt * 16 >= NQ1) return;

    const int row_a = mt * 16 + (lane & 15);
    const int nrow  = nt * 16 + (lane & 15);
    const int nclamp = nrow < NQ1 ? nrow : (NQ1 - 1);
    const int koff = (lane >> 4) * 8;

    const unsigned short* pa = tanhb + (size_t)row_a * 256 + koff;
    const unsigned short* pb = wob_bf + (size_t)nclamp * 256 + koff;

    f32x4 acc = {0.f, 0.f, 0.f, 0.f};
#pragma unroll
    for (int kk = 0; kk < 8; kk++) {
        short8 a = *(const short8*)(pa + kk * 32);
        short8 b = *(const short8*)(pb + kk * 32);
        acc = __builtin_amdgcn_mfma_f32_16x16x32_bf16(a, b, acc, 0, 0, 0);
    }

    const int col = nt * 16 + (lane & 15);
    if (col < NQ1) {
        float bias = bob[col];
        int r0 = mt * 16 + (lane >> 4) * 4;
#pragma unroll
        for (int r = 0; r < 4; r++) {
            float x = acc[r] + bias;
            out[(size_t)(r0 + r) * NQ1 + col] = sigmoidf_(x);
        }
    }
}

// ---------------------------------------------------------------------------

extern "C" void kernel_launch(void* const* d_in, const int* in_sizes, int n_in,
                              void* d_out, int out_size, void* d_ws, size_t ws_size,
                              hipStream_t stream) {
    const int* qd = (const int*)d_in[0];
    const int* ad = (const int*)d_in[1];
    const float* q_embed    = (const float*)d_in[2];
    const float* a_embed    = (const float*)d_in[3];
    const float* key_matrix = (const float*)d_in[4];
    const float* value_init = (const float*)d_in[5];
    const float* Wk  = (const float*)d_in[6];
    const float* bk  = (const float*)d_in[7];
    const float* We  = (const float*)d_in[8];
    const float* be  = (const float*)d_in[9];
    const float* We2 = (const float*)d_in[10];
    const float* be2 = (const float*)d_in[11];
    const float* Wa  = (const float*)d_in[12];
    const float* ba  = (const float*)d_in[13];
    const float* Wa2 = (const float*)d_in[14];
    const float* ba2 = (const float*)d_in[15];
    const float* Ws  = (const float*)d_in[16];
    const float* bs  = (const float*)d_in[17];
    const float* Wo  = (const float*)d_in[18];
    const float* bo  = (const float*)d_in[19];
    const float* Wsb = (const float*)d_in[20];
    const float* bsb = (const float*)d_in[21];
    const float* Wob = (const float*)d_in[22];
    const float* bob = (const float*)d_in[23];

    // workspace layout
    float* corr  = (float*)d_ws;                 // B*T*C
    float* erase = corr  + (size_t)BB * TT * CC; // B*T*V
    float* addb  = erase + (size_t)BB * TT * VV;
    float* rc    = addb  + (size_t)BB * TT * VV; // B*TM1*V
    float* rcn   = rc    + (size_t)BB * TM1 * VV;
    unsigned short* tanhb  = (unsigned short*)(rcn + (size_t)BB * TM1 * VV); // M x 256 bf16
    unsigned short* wob_bf = tanhb + (size_t)BB * TM1 * SS;                  // 5001 x 256 bf16

    float* pred_out = (float*)d_out;                    // 25472 fp32
    float* mat_out  = pred_out + (size_t)BB * TM1;      // 25472 x 5001 fp32

    int n4 = (NQ1 * SS) / 4;  // 320064, exact
    k_cvt<<<(n4 + 255) / 256, 256, 0, stream>>>(Wob, wob_bf, n4);

    k_front<<<(BB * TT) / 4, 128, 0, stream>>>(
        qd, ad, q_embed, a_embed, key_matrix,
        Wk, bk, We, be, We2, be2, Wa, ba, Wa2, ba2,
        corr, erase, addb);

    k_scan<<<BB, 256, 0, stream>>>(value_init, corr, erase, addb, rc, rcn);

    k_pred<<<(BB * TM1) / 4, 256, 0, stream>>>(
        qd, q_embed, rc, rcn, Ws, bs, Wo, bo, Wsb, bsb, tanhb, pred_out);

    dim3 gb(79, (BB * TM1) / 16);  // (ceil(313/4), 1592)
    k_big<<<gb, 256, 0, stream>>>(tanhb, wob_bf, bob, mat_out);
}